// Round 7
// baseline (163.293 us; speedup 1.0000x reference)
//
#include <hip/hip_runtime.h>

#define B_ 8
#define T_ 2048
#define H_ 256
#define PSTR 40                  // P LDS row stride (elems)
#define SCALE2 0.0901684403f     // (1/16) * log2(e)
#define SLOPE2 0.00563552752f    // 2^-8 * log2(e)
#define ELEMS ((size_t)B_ * T_ * H_)

typedef __attribute__((ext_vector_type(8))) short bf16x8;
typedef __attribute__((ext_vector_type(4))) float f32x4;

#define MFMA16(a, b, c) __builtin_amdgcn_mfma_f32_16x16x32_bf16((a), (b), (c), 0, 0, 0)

__device__ __forceinline__ ushort f2bf(float f) {
  unsigned u = __float_as_uint(f);
  u += 0x7FFFu + ((u >> 16) & 1u);   // RNE; finite inputs
  return (ushort)(u >> 16);
}

// async 16B/lane global->LDS DMA (contiguous: LDS = uniform base + lane*16)
__device__ __forceinline__ void gl_lds16(const ushort* g, ushort* l) {
  __builtin_amdgcn_global_load_lds(
      (const __attribute__((address_space(1))) unsigned int*)g,
      (__attribute__((address_space(3))) unsigned int*)l, 16, 0, 0);
}

// ---- prologue: blocks [0,1024) RoPE(k)->bf16 blocked ktile; [1024,2048) v transpose ----
// ktile layout: [b][it=t/32][d8=d/8][kv=t%32][8]   (16KB contiguous per (b,it) tile)
// vtile layout: [b][it][kvq=(t%32)/8][h][8]
__global__ void prep_kernel(const float* __restrict__ k, const float* __restrict__ v,
                            ushort* __restrict__ kt, ushort* __restrict__ vt) {
  __shared__ ushort tile[64][72];
  const int bid = blockIdx.x;
  const int tid = threadIdx.x;
  if (bid < 1024) {
    // K RoPE: thread = (bt, d8); reads 2x32B coalesced, writes 2x16B vector stores
    int idx = bid * 256 + tid;          // over B*T*16
    int d8 = idx & 15;
    int bt = idx >> 4;
    int t = bt & (T_ - 1);
    int b = bt >> 11;
    size_t base = (size_t)bt * H_ + d8 * 8;
    float4 a0 = *(const float4*)(k + base);
    float4 a1 = *(const float4*)(k + base + 4);
    float4 c0 = *(const float4*)(k + base + 128);
    float4 c1 = *(const float4*)(k + base + 132);
    float av[8] = {a0.x, a0.y, a0.z, a0.w, a1.x, a1.y, a1.z, a1.w};
    float cv[8] = {c0.x, c0.y, c0.z, c0.w, c1.x, c1.y, c1.z, c1.w};
    bf16x8 lo, hi;
#pragma unroll
    for (int e = 0; e < 8; ++e) {
      int j = d8 * 8 + e;
      float rv = (float)t * exp2f((float)j * -0.103810252959f) * 0.15915494309f;
      float fr = rv - floorf(rv);
      float sn = __builtin_amdgcn_sinf(fr), cs = __builtin_amdgcn_cosf(fr);
      lo[e] = (short)f2bf(av[e] * cs - cv[e] * sn);
      hi[e] = (short)f2bf(cv[e] * cs + av[e] * sn);
    }
    size_t kdst = (((size_t)(b * 64 + (t >> 5)) * 32 + d8) * 32 + (t & 31)) * 8;
    *(bf16x8*)(kt + kdst) = lo;
    *(bf16x8*)(kt + kdst + 4096) = hi;   // d8 + 16
  } else {
    // V transpose into blocked vtile, 64x64 tiles, XOR-8 swizzle in LDS
    int bid2 = bid - 1024;
    int b = bid2 >> 7, rem = bid2 & 127;
    int h0 = (rem >> 5) * 64, t0 = (rem & 31) * 64;
    int c4 = tid & 15, r0 = tid >> 4;
#pragma unroll
    for (int p = 0; p < 4; ++p) {
      int row = r0 + p * 16;
      const float4 f = *(const float4*)(v + ((size_t)(b * T_ + t0 + row)) * H_ + h0 + c4 * 4);
      ushort4 u;
      u.x = f2bf(f.x); u.y = f2bf(f.y); u.z = f2bf(f.z); u.w = f2bf(f.w);
      *(ushort4*)&tile[row][(c4 * 4) ^ (8 * ((row >> 3) & 7))] = u;
    }
    __syncthreads();
#pragma unroll
    for (int p = 0; p < 2; ++p) {
      int c = tid + p * 256;
      int h = c >> 3, tc = (c & 7) * 8;
      int xo = 8 * (c & 7);
      ushort4 u0, u1;
      u0.x = tile[tc + 0][h ^ xo]; u0.y = tile[tc + 1][h ^ xo];
      u0.z = tile[tc + 2][h ^ xo]; u0.w = tile[tc + 3][h ^ xo];
      u1.x = tile[tc + 4][h ^ xo]; u1.y = tile[tc + 5][h ^ xo];
      u1.z = tile[tc + 6][h ^ xo]; u1.w = tile[tc + 7][h ^ xo];
      int tg = t0 + tc;
      size_t dst = (((size_t)(b * 64 + (tg >> 5)) * 4 + ((tg >> 3) & 3)) * 256 + (h0 + h)) * 8;
      *(ushort4*)(vt + dst) = u0;
      *(ushort4*)(vt + dst + 4) = u1;
    }
  }
}

// ---- Flash attention, single-barrier iteration:
// 512 thr = 8 waves = 2 kv-groups x 4 waves x 16 q-rows (q-tile 64),
// grid (8,32) = 256 blocks = 1/CU, 2 waves/SIMD. K triple-buffered via
// gl_lds DMA (3 bufs => prefetch target was last read at iter it-1, whose
// reads completed before this iter's acquire barrier => NO release barrier,
// NO lgkm drain). V loaded straight to registers from L2-resident vt, one
// tile ahead (T14). ISSUE ORDER: V(it+1) before K(it+2), so the acquire's
// in-order vmcnt(4) drains exactly [K(it), V(it)] and leaves K(it+1) in
// flight. Max-free softmax: additive partials combined in LDS, one write.
__global__ __launch_bounds__(512, 1)
void attn_kernel(const float* __restrict__ q, const ushort* __restrict__ kt,
                 const ushort* __restrict__ vt, float* __restrict__ out) {
  // manual LDS carve: K region reused as f32 partial-exchange in epilogue
  __shared__ __align__(16) char smem[108800];
  ushort* Kbase = (ushort*)smem;             // [g][3][8192] ush = 96 KB
  ushort* Pbase = (ushort*)(smem + 98304);   // [8][16*PSTR]  10 KB
  float*  Lsh   = (float*)(smem + 108544);   // 64 floats
  float*  Ofl   = (float*)smem;              // epilogue reuse [64][260] f32

  const int tid = threadIdx.x;
  const int w = tid >> 6, lane = tid & 63, quad = lane >> 4, l16 = lane & 15;
  const int g = w >> 2;                 // kv-half group
  const int wl = w & 3;                 // wave index within group
  const int gt = tid & 255;             // thread index within group
  const int b = blockIdx.x;             // linear%8==b -> XCD affinity
  const int q0 = blockIdx.y * 64;
  const int kvb0 = g * (T_ / 2);

  ushort* Kgrp = Kbase + g * 24576;     // this group's [3][8192]
  ushort* Psh = Pbase + w * (16 * PSTR);

  // ---- in-register RoPE of this wave's 16 Q rows into A-frags ----
  bf16x8 aq[8];
  {
    const float* qb = q + ((size_t)(b * T_) + q0 + wl * 16) * H_;
    const int t = q0 + wl * 16 + l16;
    float qv[8][8];
#pragma unroll
    for (int ks = 0; ks < 8; ++ks) {
      float4 x0 = *(const float4*)(qb + (size_t)l16 * H_ + ks * 32 + quad * 8);
      float4 x1 = *(const float4*)(qb + (size_t)l16 * H_ + ks * 32 + quad * 8 + 4);
      qv[ks][0] = x0.x; qv[ks][1] = x0.y; qv[ks][2] = x0.z; qv[ks][3] = x0.w;
      qv[ks][4] = x1.x; qv[ks][5] = x1.y; qv[ks][6] = x1.z; qv[ks][7] = x1.w;
    }
#pragma unroll
    for (int ks = 0; ks < 4; ++ks)
#pragma unroll
      for (int e = 0; e < 8; ++e) {
        int d = ks * 32 + quad * 8 + e;
        float rv = (float)t * exp2f((float)d * -0.103810252959f) * 0.15915494309f;
        float fr = rv - floorf(rv);
        float sn = __builtin_amdgcn_sinf(fr), cs = __builtin_amdgcn_cosf(fr);
        aq[ks][e]     = (short)f2bf(qv[ks][e] * cs - qv[ks + 4][e] * sn);
        aq[ks + 4][e] = (short)f2bf(qv[ks + 4][e] * cs + qv[ks][e] * sn);
      }
  }

  const f32x4 fzero = {0.f, 0.f, 0.f, 0.f};
  f32x4 O[16], lac = fzero;
#pragma unroll
  for (int ht = 0; ht < 16; ++ht) O[ht] = fzero;
  bf16x8 vones;
#pragma unroll
  for (int i = 0; i < 8; ++i) vones[i] = (short)0x3F80;

  // group g streams tiles [g*32, g*32+32) of this b
  const ushort* ktb = kt + (size_t)(b * 64 + g * 32) * 8192;
  const ushort* vtb = vt + (size_t)(b * 64 + g * 32) * 8192;
  const int stoff = gt * 8;             // 16B/lane over 256 group threads
  const int vro = (quad * 256 + l16) * 8;   // this thread's V-frag base (elems)

  // prologue issue order pins the vmcnt ledger: K0(4), V0(16), K1(4)
#pragma unroll
  for (int i = 0; i < 4; ++i)
    gl_lds16(ktb + stoff + i * 2048, Kgrp + stoff + i * 2048);
  __builtin_amdgcn_sched_barrier(0);
  bf16x8 vr[16];
#pragma unroll
  for (int ht = 0; ht < 16; ++ht)
    vr[ht] = *(const bf16x8*)(vtb + vro + ht * 128);
  __builtin_amdgcn_sched_barrier(0);
#pragma unroll
  for (int i = 0; i < 4; ++i)
    gl_lds16(ktb + 8192 + stoff + i * 2048, Kgrp + 8192 + stoff + i * 2048);

  const float arb = SLOPE2 * (float)(q0 + wl * 16 + quad * 4);

  for (int it = 0; it < 32; ++it) {
    const int c = it % 3;
    // acquire: outstanding (oldest->newest) = [K(it):4, V(it):16, K(it+1):4].
    // vmcnt(4) drains K(it)+V(it), keeps K(it+1) in flight. Last iter: 0.
    __builtin_amdgcn_sched_barrier(0);
    if (it == 31) __builtin_amdgcn_s_waitcnt(0x0F70);   // vmcnt(0)
    else          __builtin_amdgcn_s_waitcnt(0x0F74);   // vmcnt(4)
    __builtin_amdgcn_s_barrier();
    __builtin_amdgcn_sched_barrier(0);

    const ushort* Kc = Kgrp + c * 8192;

    // QK on Kc
    f32x4 s[2] = {fzero, fzero};
#pragma unroll
    for (int ks = 0; ks < 8; ++ks)
#pragma unroll
      for (int nt = 0; nt < 2; ++nt) {
        bf16x8 kf = *(const bf16x8*)&Kc[((ks * 4 + quad) * 32 + nt * 16 + l16) * 8];
        s[nt] = MFMA16(aq[ks], kf, s[nt]);
      }

    // p = exp2(s*SCALE2 + SLOPE2*(col-row)) -> wave-private Psh
#pragma unroll
    for (int nt = 0; nt < 2; ++nt) {
      float ac = SLOPE2 * (float)(kvb0 + it * 32 + nt * 16 + l16);
#pragma unroll
      for (int r = 0; r < 4; ++r) {
        float a0 = ac - arb - SLOPE2 * (float)r;
        float pv = __builtin_amdgcn_exp2f(fmaf(s[nt][r], SCALE2, a0));
        Psh[(quad * 4 + r) * PSTR + nt * 16 + l16] = f2bf(pv);
      }
    }

    // PV + rowsum via ones-MFMA; V comes from registers (no LDS)
    bf16x8 pf = *(const bf16x8*)&Psh[l16 * PSTR + quad * 8];
    lac = MFMA16(pf, vones, lac);
#pragma unroll
    for (int ht = 0; ht < 16; ++ht)
      O[ht] = MFMA16(pf, vr[ht], O[ht]);

    // prefetch V(it+1) into registers FIRST (so the next acquire's vmcnt(4)
    // covers it), THEN K(it+2) DMA into the 3-buf slot last read at it-1.
    __builtin_amdgcn_sched_barrier(0);
    if (it < 31) {
      const ushort* vg = vtb + (size_t)(it + 1) * 8192;
#pragma unroll
      for (int ht = 0; ht < 16; ++ht)
        vr[ht] = *(const bf16x8*)(vg + vro + ht * 128);
    }
    __builtin_amdgcn_sched_barrier(0);
    if (it < 30) {
      const ushort* kg = ktb + (size_t)(it + 2) * 8192;
      ushort* kd = Kgrp + ((it + 2) % 3) * 8192;
#pragma unroll
      for (int i = 0; i < 4; ++i)
        gl_lds16(kg + stoff + i * 2048, kd + stoff + i * 2048);
    }
  }

  // ---- in-LDS combine: additive partials (max-free softmax) ----
  __syncthreads();                      // all K reads retired; K region reusable
  if (g == 1) {
#pragma unroll
    for (int r = 0; r < 4; ++r) {
      int row = wl * 16 + quad * 4 + r;
#pragma unroll
      for (int ht = 0; ht < 16; ++ht)
        Ofl[row * 260 + ht * 16 + l16] = O[ht][r];
      if (l16 == 0) Lsh[row] = lac[r];
    }
  }
  __syncthreads();
  if (g == 0) {
    float* ob = out + ((size_t)(b * T_) + q0 + wl * 16) * H_;
#pragma unroll
    for (int r = 0; r < 4; ++r) {
      int row = wl * 16 + quad * 4 + r;
      float inv = 1.0f / (lac[r] + Lsh[row]);
#pragma unroll
      for (int ht = 0; ht < 16; ++ht)
        ob[(size_t)(quad * 4 + r) * H_ + ht * 16 + l16] =
            (O[ht][r] + Ofl[row * 260 + ht * 16 + l16]) * inv;
    }
  }
}

extern "C" void kernel_launch(void* const* d_in, const int* in_sizes, int n_in,
                              void* d_out, int out_size, void* d_ws, size_t ws_size,
                              hipStream_t stream) {
  const float* q = (const float*)d_in[0];
  const float* k = (const float*)d_in[1];
  const float* v = (const float*)d_in[2];
  float* out = (float*)d_out;

  ushort* kt = (ushort*)d_ws;
  ushort* vt = kt + ELEMS;

  prep_kernel<<<dim3(2048), 256, 0, stream>>>(k, v, kt, vt);
  attn_kernel<<<dim3(B_, T_ / 64), 512, 0, stream>>>(q, kt, vt, out);
}

// Round 8
// 145.516 us; speedup vs baseline: 1.1222x; 1.1222x over previous
//
#include <hip/hip_runtime.h>

#define B_ 8
#define T_ 2048
#define H_ 256
#define PSTR 72                  // P LDS row stride (elems), 64+8 pad
#define SCALE2 0.0901684403f     // (1/16) * log2(e)
#define SLOPE2 0.00563552752f    // 2^-8 * log2(e)
#define ELEMS ((size_t)B_ * T_ * H_)

typedef __attribute__((ext_vector_type(8))) short bf16x8;
typedef __attribute__((ext_vector_type(4))) float f32x4;

#define MFMA16(a, b, c) __builtin_amdgcn_mfma_f32_16x16x32_bf16((a), (b), (c), 0, 0, 0)

__device__ __forceinline__ ushort f2bf(float f) {
  unsigned u = __float_as_uint(f);
  u += 0x7FFFu + ((u >> 16) & 1u);   // RNE; finite inputs
  return (ushort)(u >> 16);
}

// async 16B/lane global->LDS DMA (contiguous: LDS = uniform base + lane*16)
__device__ __forceinline__ void gl_lds16(const ushort* g, ushort* l) {
  __builtin_amdgcn_global_load_lds(
      (const __attribute__((address_space(1))) unsigned int*)g,
      (__attribute__((address_space(3))) unsigned int*)l, 16, 0, 0);
}

// ---- prologue: blocks [0,1024) RoPE(k)->bf16 blocked ktile; [1024,2048) v transpose ----
// ktile layout: [b][it=t/32][d8=d/8][kv=t%32][8]   (16KB contiguous per (b,it) tile)
// vtile layout: [b][it][kvq=(t%32)/8][h][8]
__global__ void prep_kernel(const float* __restrict__ k, const float* __restrict__ v,
                            ushort* __restrict__ kt, ushort* __restrict__ vt) {
  __shared__ ushort tile[64][72];
  const int bid = blockIdx.x;
  const int tid = threadIdx.x;
  if (bid < 1024) {
    // K RoPE: thread = (bt, d8); reads 2x32B coalesced, writes 2x16B vector stores
    int idx = bid * 256 + tid;          // over B*T*16
    int d8 = idx & 15;
    int bt = idx >> 4;
    int t = bt & (T_ - 1);
    int b = bt >> 11;
    size_t base = (size_t)bt * H_ + d8 * 8;
    float4 a0 = *(const float4*)(k + base);
    float4 a1 = *(const float4*)(k + base + 4);
    float4 c0 = *(const float4*)(k + base + 128);
    float4 c1 = *(const float4*)(k + base + 132);
    float av[8] = {a0.x, a0.y, a0.z, a0.w, a1.x, a1.y, a1.z, a1.w};
    float cv[8] = {c0.x, c0.y, c0.z, c0.w, c1.x, c1.y, c1.z, c1.w};
    bf16x8 lo, hi;
#pragma unroll
    for (int e = 0; e < 8; ++e) {
      int j = d8 * 8 + e;
      float rv = (float)t * exp2f((float)j * -0.103810252959f) * 0.15915494309f;
      float fr = rv - floorf(rv);
      float sn = __builtin_amdgcn_sinf(fr), cs = __builtin_amdgcn_cosf(fr);
      lo[e] = (short)f2bf(av[e] * cs - cv[e] * sn);
      hi[e] = (short)f2bf(cv[e] * cs + av[e] * sn);
    }
    size_t kdst = (((size_t)(b * 64 + (t >> 5)) * 32 + d8) * 32 + (t & 31)) * 8;
    *(bf16x8*)(kt + kdst) = lo;
    *(bf16x8*)(kt + kdst + 4096) = hi;   // d8 + 16
  } else {
    // V transpose into blocked vtile, 64x64 tiles, XOR-8 swizzle in LDS
    int bid2 = bid - 1024;
    int b = bid2 >> 7, rem = bid2 & 127;
    int h0 = (rem >> 5) * 64, t0 = (rem & 31) * 64;
    int c4 = tid & 15, r0 = tid >> 4;
#pragma unroll
    for (int p = 0; p < 4; ++p) {
      int row = r0 + p * 16;
      const float4 f = *(const float4*)(v + ((size_t)(b * T_ + t0 + row)) * H_ + h0 + c4 * 4);
      ushort4 u;
      u.x = f2bf(f.x); u.y = f2bf(f.y); u.z = f2bf(f.z); u.w = f2bf(f.w);
      *(ushort4*)&tile[row][(c4 * 4) ^ (8 * ((row >> 3) & 7))] = u;
    }
    __syncthreads();
#pragma unroll
    for (int p = 0; p < 2; ++p) {
      int c = tid + p * 256;
      int h = c >> 3, tc = (c & 7) * 8;
      int xo = 8 * (c & 7);
      ushort4 u0, u1;
      u0.x = tile[tc + 0][h ^ xo]; u0.y = tile[tc + 1][h ^ xo];
      u0.z = tile[tc + 2][h ^ xo]; u0.w = tile[tc + 3][h ^ xo];
      u1.x = tile[tc + 4][h ^ xo]; u1.y = tile[tc + 5][h ^ xo];
      u1.z = tile[tc + 6][h ^ xo]; u1.w = tile[tc + 7][h ^ xo];
      int tg = t0 + tc;
      size_t dst = (((size_t)(b * 64 + (tg >> 5)) * 4 + ((tg >> 3) & 3)) * 256 + (h0 + h)) * 8;
      *(ushort4*)(vt + dst) = u0;
      *(ushort4*)(vt + dst + 4) = u1;
    }
  }
}

// ---- Flash attention: R1 structure with KVBLK=64 (barrier amortization).
// 512-thr blocks, 8 waves x 16 q-rows, q-tile 128, kv-split 2 (blockIdx.z).
// 16 iterations of kv-64; per iter: 32 QK + 34 PV MFMAs between the same
// 2-barrier chain R1 had (acquire vmcnt(8) / lgkm-only release). K,V double-
// buffered 32KB tiles (= 2 adjacent 16KB prep sub-tiles, contiguous). LDS
// 146 KB -> 1 block/CU, 2 waves/SIMD (same occupancy as R1: clean A/B).
__global__ __launch_bounds__(512, 2)
void attn_kernel(const float* __restrict__ q, const ushort* __restrict__ kt,
                 const ushort* __restrict__ vt, float* __restrict__ out,
                 float* __restrict__ o1, float* __restrict__ lpart) {
  __shared__ ushort Ksh[2][16384];      // [buf][half][d8][kv32][8]  64 KB
  __shared__ ushort Vsh[2][16384];      // [buf][half][kvq][h256][8] 64 KB
  __shared__ ushort Psh[8][16 * PSTR];  // per-wave P [16 rows][64+8] 18 KB

  const int tid = threadIdx.x;
  const int w = tid >> 6, lane = tid & 63, quad = lane >> 4, l16 = lane & 15;
  const int b = blockIdx.x;             // linear%8==b -> XCD affinity
  const int q0 = blockIdx.y * 128;
  const int sp = blockIdx.z;
  const int kvb = sp * (T_ / 2);
  const int niter = 16;                 // (T/2)/64

  // ---- in-register RoPE of this wave's 16 Q rows into A-frags ----
  bf16x8 aq[8];
  {
    const float* qb = q + ((size_t)(b * T_) + q0 + w * 16) * H_;
    const int t = q0 + w * 16 + l16;
    float qv[8][8];
#pragma unroll
    for (int ks = 0; ks < 8; ++ks) {
      float4 x0 = *(const float4*)(qb + (size_t)l16 * H_ + ks * 32 + quad * 8);
      float4 x1 = *(const float4*)(qb + (size_t)l16 * H_ + ks * 32 + quad * 8 + 4);
      qv[ks][0] = x0.x; qv[ks][1] = x0.y; qv[ks][2] = x0.z; qv[ks][3] = x0.w;
      qv[ks][4] = x1.x; qv[ks][5] = x1.y; qv[ks][6] = x1.z; qv[ks][7] = x1.w;
    }
#pragma unroll
    for (int ks = 0; ks < 4; ++ks)
#pragma unroll
      for (int e = 0; e < 8; ++e) {
        int d = ks * 32 + quad * 8 + e;
        float rv = (float)t * exp2f((float)d * -0.103810252959f) * 0.15915494309f;
        float fr = rv - floorf(rv);
        float sn = __builtin_amdgcn_sinf(fr), cs = __builtin_amdgcn_cosf(fr);
        aq[ks][e]     = (short)f2bf(qv[ks][e] * cs - qv[ks + 4][e] * sn);
        aq[ks + 4][e] = (short)f2bf(qv[ks + 4][e] * cs + qv[ks][e] * sn);
      }
  }

  const f32x4 fzero = {0.f, 0.f, 0.f, 0.f};
  f32x4 O[16], lac = fzero;
#pragma unroll
  for (int ht = 0; ht < 16; ++ht) O[ht] = fzero;
  bf16x8 vones;
#pragma unroll
  for (int i = 0; i < 8; ++i) vones[i] = (short)0x3F80;

  // this split's stream: 32 KB tiles, contiguous in kt/vt
  const ushort* ktb = kt + (size_t)(b * 64 + sp * 32) * 8192;
  const ushort* vtb = vt + (size_t)(b * 64 + sp * 32) * 8192;
  const int stoff = tid * 8;            // 16B/lane over 512 threads = 8KB/DMA

  // preload tiles 0,1 (per tile: 4 K-DMA + 4 V-DMA per thread)
#pragma unroll
  for (int tt = 0; tt < 2; ++tt) {
    const ushort* kg = ktb + (size_t)tt * 16384;
    const ushort* vg = vtb + (size_t)tt * 16384;
#pragma unroll
    for (int i = 0; i < 4; ++i) {
      gl_lds16(kg + stoff + i * 4096, &Ksh[tt][stoff + i * 4096]);
      gl_lds16(vg + stoff + i * 4096, &Vsh[tt][stoff + i * 4096]);
    }
  }

  const float arb = SLOPE2 * (float)(q0 + w * 16 + quad * 4);

  for (int it = 0; it < niter; ++it) {
    const int p = it & 1;
    // acquire: tile(it)'s 8 DMAs landed (issued 2 iters ago); tile(it+1)'s 8 in flight
    __builtin_amdgcn_sched_barrier(0);
    if (it == niter - 1) __builtin_amdgcn_s_waitcnt(0x0070);   // vmcnt(0) lgkm(0)
    else                 __builtin_amdgcn_s_waitcnt(0x0F78);   // vmcnt(8)
    __builtin_amdgcn_s_barrier();
    __builtin_amdgcn_sched_barrier(0);

    // QK over 64 kv: nt 0..3, halves of the 32KB tile at +8192 elems
    f32x4 s[4] = {fzero, fzero, fzero, fzero};
#pragma unroll
    for (int ks = 0; ks < 8; ++ks)
#pragma unroll
      for (int nt = 0; nt < 4; ++nt) {
        bf16x8 kf = *(const bf16x8*)&Ksh[p][(nt >> 1) * 8192 +
            ((ks * 4 + quad) * 32 + (nt & 1) * 16 + l16) * 8];
        s[nt] = MFMA16(aq[ks], kf, s[nt]);
      }

    // p = exp2(s*SCALE2 + SLOPE2*(col-row)) -> wave-private Psh [16][72]
#pragma unroll
    for (int nt = 0; nt < 4; ++nt) {
      float ac = SLOPE2 * (float)(kvb + it * 64 + nt * 16 + l16);
#pragma unroll
      for (int r = 0; r < 4; ++r) {
        float a0 = ac - arb - SLOPE2 * (float)r;
        float pv = __builtin_amdgcn_exp2f(fmaf(s[nt][r], SCALE2, a0));
        Psh[w][(quad * 4 + r) * PSTR + nt * 16 + l16] = f2bf(pv);
      }
    }

    // PV over 64 kv (two 32-kv slabs) + rowsum via ones-MFMA
    bf16x8 pf0 = *(const bf16x8*)&Psh[w][l16 * PSTR + quad * 8];
    bf16x8 pf1 = *(const bf16x8*)&Psh[w][l16 * PSTR + 32 + quad * 8];
    lac = MFMA16(pf0, vones, lac);
    lac = MFMA16(pf1, vones, lac);
#pragma unroll
    for (int ht = 0; ht < 16; ++ht) {
      bf16x8 vf0 = *(const bf16x8*)&Vsh[p][(quad * 256 + ht * 16 + l16) * 8];
      bf16x8 vf1 = *(const bf16x8*)&Vsh[p][8192 + (quad * 256 + ht * 16 + l16) * 8];
      O[ht] = MFMA16(pf0, vf0, O[ht]);
      O[ht] = MFMA16(pf1, vf1, O[ht]);
    }

    // release: drain this wave's LDS reads, then barrier -> buf[p] free
    __builtin_amdgcn_sched_barrier(0);
    __builtin_amdgcn_s_waitcnt(0xC07F);   // lgkmcnt(0) only
    __builtin_amdgcn_s_barrier();
    __builtin_amdgcn_sched_barrier(0);

    // prefetch tile(it+2) into the buffer just freed
    if (it < niter - 2) {
      const ushort* kg = ktb + (size_t)(it + 2) * 16384;
      const ushort* vg = vtb + (size_t)(it + 2) * 16384;
#pragma unroll
      for (int i = 0; i < 4; ++i) {
        gl_lds16(kg + stoff + i * 4096, &Ksh[p][stoff + i * 4096]);
        gl_lds16(vg + stoff + i * 4096, &Vsh[p][stoff + i * 4096]);
      }
    }
  }

  // epilogue: unnormalized O-partial + l-partial
  float* od = (sp == 0) ? out : o1;
  float* ob = od + ((size_t)(b * T_) + q0 + w * 16) * H_;
#pragma unroll
  for (int r = 0; r < 4; ++r) {
    int row = quad * 4 + r;
#pragma unroll
    for (int ht = 0; ht < 16; ++ht)
      ob[(size_t)row * H_ + ht * 16 + l16] = O[ht][r];
  }
  if (l16 == 0) {
#pragma unroll
    for (int r = 0; r < 4; ++r)
      lpart[(size_t)(sp * B_ + b) * T_ + q0 + w * 16 + quad * 4 + r] = lac[r];
  }
}

// ---- combine: out = (O0 + O1) / (l0 + l1) ----
__global__ void combine_kernel(float* __restrict__ out, const float* __restrict__ o1,
                               const float* __restrict__ lpart) {
  int idx = blockIdx.x * 256 + threadIdx.x;   // over B*T*H/4
  int row = idx >> 6;
  float inv = 1.0f / (lpart[row] + lpart[B_ * T_ + row]);
  float4 a = ((const float4*)out)[idx];
  float4 c = ((const float4*)o1)[idx];
  a.x = (a.x + c.x) * inv; a.y = (a.y + c.y) * inv;
  a.z = (a.z + c.z) * inv; a.w = (a.w + c.w) * inv;
  ((float4*)out)[idx] = a;
}

extern "C" void kernel_launch(void* const* d_in, const int* in_sizes, int n_in,
                              void* d_out, int out_size, void* d_ws, size_t ws_size,
                              hipStream_t stream) {
  const float* q = (const float*)d_in[0];
  const float* k = (const float*)d_in[1];
  const float* v = (const float*)d_in[2];
  float* out = (float*)d_out;

  ushort* kt = (ushort*)d_ws;
  ushort* vt = kt + ELEMS;
  float* o1 = (float*)(vt + ELEMS);
  float* lpart = o1 + ELEMS;            // 2*B*T floats

  prep_kernel<<<dim3(2048), 256, 0, stream>>>(k, v, kt, vt);
  attn_kernel<<<dim3(B_, T_ / 128, 2), 512, 0, stream>>>(q, kt, vt, out, o1, lpart);
  combine_kernel<<<dim3((B_ * T_ * H_ / 4) / 256), 256, 0, stream>>>(out, o1, lpart);
}